// Round 5
// baseline (60.680 us; speedup 1.0000x reference)
//
#include <hip/hip_runtime.h>

#define NDIM 1024
#define BATCH 16

typedef float fvec4 __attribute__((ext_vector_type(4)));

// Raw (pre-shuffle) patch: 3 vec4 rows + one lane-selected halo scalar per row
// (lane tx==0 holds the left halo, lane tx==15 holds the right halo).
struct Patch {
    fvec4 m0, m1, m2;
    float h0, h1, h2;
};

// Fused spatially-varying 3x3 filter:
//   K[p,i,j] = bias[p] + sum_{m,n} w[p,0,m,n] * image_pad[i+m, j+n]
//   y[b,i,j] = sum_{k,l} K[3k+l,i,j] * x_pad[b, i+k, j+l]
// One block owns a 64x16 pixel tile for ALL 16 batches (K built once per
// pixel). 3-deep rotating prefetch across batches; halos via lane shuffles
// (strided 64-lane scalar loads were the R1/R3 TA-line bottleneck), with a
// single merged exec-masked load for the two tile-edge columns.
__global__ __launch_bounds__(256, 4) void smallsm_fused(
    const float* __restrict__ image,
    const float* __restrict__ x,
    const float* __restrict__ w,
    const float* __restrict__ bias,
    float* __restrict__ out)
{
    const int N = NDIM;
    const int tx = threadIdx.x & 15;   // 16 threads in j (x4 pixels = 64 cols)
    const int ty = threadIdx.x >> 4;   // 16 threads in i
    const int j0 = (blockIdx.x * 16 + tx) * 4;
    const int i  = blockIdx.y * 16 + ty;

    const bool is_l = (tx == 0);
    const bool is_r = (tx == 15);
    const bool hp   = (is_l && j0 > 0) || (is_r && j0 + 4 < N);
    const int  hoff = is_r ? (j0 + 4) : (j0 - 1);   // lane-selected halo column

    // Issue loads for one 3-row patch. No waits consumed here.
    auto issue_patch = [&](const float* __restrict__ base, Patch& p) {
#pragma unroll
        for (int r = 0; r < 3; ++r) {
            const int row = i - 1 + r;
            const bool rv = (row >= 0) && (row < N);
            const float* rp = base + (size_t)row * N;
            fvec4 mv = {0.f, 0.f, 0.f, 0.f};
            if (rv) mv = *reinterpret_cast<const fvec4*>(rp + j0);
            float hv = 0.f;
            if (rv && hp) hv = rp[hoff];     // one masked load, lanes {0,15}/group
            if (r == 0) { p.m0 = mv; p.h0 = hv; }
            if (r == 1) { p.m1 = mv; p.h1 = hv; }
            if (r == 2) { p.m2 = mv; p.h2 = hv; }
        }
    };

    // Raw patch -> 3x6 window via neighbor-lane shuffles.
    auto finish_patch = [&](const Patch& p, float (&v)[3][6]) {
#pragma unroll
        for (int r = 0; r < 3; ++r) {
            const fvec4 m  = (r == 0) ? p.m0 : (r == 1) ? p.m1 : p.m2;
            const float hv = (r == 0) ? p.h0 : (r == 1) ? p.h1 : p.h2;
            float left  = __shfl_up(m.w, 1);    // lane tx-1's last element
            float right = __shfl_down(m.x, 1);  // lane tx+1's first element
            if (is_l) left  = hv;               // crossed 16-lane row group
            if (is_r) right = hv;
            v[r][0] = left; v[r][1] = m.x; v[r][2] = m.y;
            v[r][3] = m.z;  v[r][4] = m.w; v[r][5] = right;
        }
    };

    float K[9][4];

    auto apply_store = [&](const float (&v)[3][6], int b) {
        float a0 = 0.f, a1 = 0.f, a2 = 0.f, a3 = 0.f;
#pragma unroll
        for (int k = 0; k < 3; ++k) {
#pragma unroll
            for (int l = 0; l < 3; ++l) {
                const int p = 3 * k + l;
                a0 += K[p][0] * v[k][l + 0];
                a1 += K[p][1] * v[k][l + 1];
                a2 += K[p][2] * v[k][l + 2];
                a3 += K[p][3] * v[k][l + 3];
            }
        }
        fvec4 res; res.x = a0; res.y = a1; res.z = a2; res.w = a3;
        fvec4* dst = reinterpret_cast<fvec4*>(
            out + (size_t)b * N * N + (size_t)i * N + j0);
        __builtin_nontemporal_store(res, dst);
    };

    // --- prologue: image + 3 batches of x in flight ---
    const size_t NN = (size_t)N * N;
    Patch pim, P[3];
    issue_patch(image, pim);
    issue_patch(x + 0 * NN, P[0]);
    issue_patch(x + 1 * NN, P[1]);
    issue_patch(x + 2 * NN, P[2]);

    // --- per-pixel kernels K[9][4] (waits only on image loads) ---
    {
        float im[3][6];
        finish_patch(pim, im);
#pragma unroll
        for (int p = 0; p < 9; ++p) {
            const float bv = bias[p];
            float a0 = bv, a1 = bv, a2 = bv, a3 = bv;
#pragma unroll
            for (int m = 0; m < 3; ++m) {
#pragma unroll
                for (int n = 0; n < 3; ++n) {
                    const float wv = w[p * 9 + m * 3 + n];
                    a0 += wv * im[m][0 + n];
                    a1 += wv * im[m][1 + n];
                    a2 += wv * im[m][2 + n];
                    a3 += wv * im[m][3 + n];
                }
            }
            K[p][0] = a0; K[p][1] = a1; K[p][2] = a2; K[p][3] = a3;
        }
    }

    // --- 16-batch pipeline: consume P[t%3], immediately refill it with
    //     batch t+3, then do the FMAs+store while those loads fly. ---
#pragma unroll
    for (int t = 0; t < BATCH; ++t) {
        float v[3][6];
        finish_patch(P[t % 3], v);              // vmcnt-waits batch t only
        if (t + 3 < BATCH)
            issue_patch(x + (size_t)(t + 3) * NN, P[t % 3]);
        apply_store(v, t);
    }
}

extern "C" void kernel_launch(void* const* d_in, const int* in_sizes, int n_in,
                              void* d_out, int out_size, void* d_ws, size_t ws_size,
                              hipStream_t stream) {
    const float* image = (const float*)d_in[0];
    const float* x     = (const float*)d_in[1];
    const float* w     = (const float*)d_in[2];
    const float* bias  = (const float*)d_in[3];
    float* out = (float*)d_out;

    dim3 grid(NDIM / 64, NDIM / 16, 1);
    dim3 block(256);
    hipLaunchKernelGGL(smallsm_fused, grid, block, 0, stream,
                       image, x, w, bias, out);
}

// Round 6
// 60.282 us; speedup vs baseline: 1.0066x; 1.0066x over previous
//
#include <hip/hip_runtime.h>

#define NDIM 1024
#define BATCH 16

typedef float fvec4 __attribute__((ext_vector_type(4)));

// Raw (pre-shuffle) patch: 3 vec4 rows + one lane-selected halo scalar per row
// (lane tx==0 holds the left halo, lane tx==15 holds the right halo).
struct Patch {
    fvec4 m0, m1, m2;
    float h0, h1, h2;
};

// Fused spatially-varying 3x3 filter:
//   K[p,i,j] = bias[p] + sum_{m,n} w[p,0,m,n] * image_pad[i+m, j+n]
//   y[b,i,j] = sum_{k,l} K[3k+l,i,j] * x_pad[b, i+k, j+l]
// One block owns a 64x16 pixel tile for ALL 16 batches (K built once per
// pixel; grid = 1024 blocks = exactly 4 resident blocks/CU). 3-deep rotating
// prefetch with STATICALLY NAMED buffers (R5's P[t%3] array went to scratch:
// +40MB WRITE_SIZE of spills). Halos via lane shuffles, not strided loads.
__global__ __launch_bounds__(256, 4) void smallsm_fused(
    const float* __restrict__ image,
    const float* __restrict__ x,
    const float* __restrict__ w,
    const float* __restrict__ bias,
    float* __restrict__ out)
{
    const int N = NDIM;
    const int tx = threadIdx.x & 15;   // 16 threads in j (x4 pixels = 64 cols)
    const int ty = threadIdx.x >> 4;   // 16 threads in i
    const int j0 = (blockIdx.x * 16 + tx) * 4;
    const int i  = blockIdx.y * 16 + ty;

    const bool is_l = (tx == 0);
    const bool is_r = (tx == 15);
    const bool hp   = (is_l && j0 > 0) || (is_r && j0 + 4 < N);
    const int  hoff = is_r ? (j0 + 4) : (j0 - 1);   // lane-selected halo column

    // Issue loads for one 3-row patch. No waits consumed here.
    auto issue_patch = [&](const float* __restrict__ base, Patch& p) {
#pragma unroll
        for (int r = 0; r < 3; ++r) {
            const int row = i - 1 + r;
            const bool rv = (row >= 0) && (row < N);
            const float* rp = base + (size_t)row * N;
            fvec4 mv = {0.f, 0.f, 0.f, 0.f};
            if (rv) mv = *reinterpret_cast<const fvec4*>(rp + j0);
            float hv = 0.f;
            if (rv && hp) hv = rp[hoff];     // one masked load, lanes {0,15}/group
            if (r == 0) { p.m0 = mv; p.h0 = hv; }
            if (r == 1) { p.m1 = mv; p.h1 = hv; }
            if (r == 2) { p.m2 = mv; p.h2 = hv; }
        }
    };

    // Raw patch -> 3x6 window via neighbor-lane shuffles.
    auto finish_patch = [&](const Patch& p, float (&v)[3][6]) {
#pragma unroll
        for (int r = 0; r < 3; ++r) {
            const fvec4 m  = (r == 0) ? p.m0 : (r == 1) ? p.m1 : p.m2;
            const float hv = (r == 0) ? p.h0 : (r == 1) ? p.h1 : p.h2;
            float left  = __shfl_up(m.w, 1);    // lane tx-1's last element
            float right = __shfl_down(m.x, 1);  // lane tx+1's first element
            if (is_l) left  = hv;               // crossed 16-lane row group
            if (is_r) right = hv;
            v[r][0] = left; v[r][1] = m.x; v[r][2] = m.y;
            v[r][3] = m.z;  v[r][4] = m.w; v[r][5] = right;
        }
    };

    float K[9][4];

    auto apply_store = [&](const float (&v)[3][6], int b) {
        float a0 = 0.f, a1 = 0.f, a2 = 0.f, a3 = 0.f;
#pragma unroll
        for (int k = 0; k < 3; ++k) {
#pragma unroll
            for (int l = 0; l < 3; ++l) {
                const int p = 3 * k + l;
                a0 += K[p][0] * v[k][l + 0];
                a1 += K[p][1] * v[k][l + 1];
                a2 += K[p][2] * v[k][l + 2];
                a3 += K[p][3] * v[k][l + 3];
            }
        }
        fvec4 res; res.x = a0; res.y = a1; res.z = a2; res.w = a3;
        fvec4* dst = reinterpret_cast<fvec4*>(
            out + (size_t)b * N * N + (size_t)i * N + j0);
        __builtin_nontemporal_store(res, dst);
    };

    // --- prologue: image + 3 batches of x in flight ---
    const size_t NN = (size_t)N * N;
    Patch pim, P0, P1, P2;            // named, never array-indexed
    issue_patch(image, pim);
    issue_patch(x + 0 * NN, P0);
    issue_patch(x + 1 * NN, P1);
    issue_patch(x + 2 * NN, P2);

    // --- per-pixel kernels K[9][4] (waits only on image loads; the 324-FMA
    //     build runs while the 3 x-batches are still in flight) ---
    {
        float im[3][6];
        finish_patch(pim, im);
#pragma unroll
        for (int p = 0; p < 9; ++p) {
            const float bv = bias[p];
            float a0 = bv, a1 = bv, a2 = bv, a3 = bv;
#pragma unroll
            for (int m = 0; m < 3; ++m) {
#pragma unroll
                for (int n = 0; n < 3; ++n) {
                    const float wv = w[p * 9 + m * 3 + n];
                    a0 += wv * im[m][0 + n];
                    a1 += wv * im[m][1 + n];
                    a2 += wv * im[m][2 + n];
                    a3 += wv * im[m][3 + n];
                }
            }
            K[p][0] = a0; K[p][1] = a1; K[p][2] = a2; K[p][3] = a3;
        }
    }

    // --- 16-batch pipeline: consume BUF (vmcnt-waits batch T only),
    //     refill BUF with batch T+3, FMAs+store while those loads fly. ---
#define STEP(T, BUF) do {                                        \
        float v[3][6];                                           \
        finish_patch(BUF, v);                                    \
        if ((T) + 3 < BATCH)                                     \
            issue_patch(x + (size_t)((T) + 3) * NN, BUF);        \
        apply_store(v, (T));                                     \
    } while (0)

    STEP(0,  P0); STEP(1,  P1); STEP(2,  P2);
    STEP(3,  P0); STEP(4,  P1); STEP(5,  P2);
    STEP(6,  P0); STEP(7,  P1); STEP(8,  P2);
    STEP(9,  P0); STEP(10, P1); STEP(11, P2);
    STEP(12, P0); STEP(13, P1); STEP(14, P2);
    STEP(15, P0);
#undef STEP
}

extern "C" void kernel_launch(void* const* d_in, const int* in_sizes, int n_in,
                              void* d_out, int out_size, void* d_ws, size_t ws_size,
                              hipStream_t stream) {
    const float* image = (const float*)d_in[0];
    const float* x     = (const float*)d_in[1];
    const float* w     = (const float*)d_in[2];
    const float* bias  = (const float*)d_in[3];
    float* out = (float*)d_out;

    dim3 grid(NDIM / 64, NDIM / 16, 1);
    dim3 block(256);
    hipLaunchKernelGGL(smallsm_fused, grid, block, 0, stream,
                       image, x, w, bias, out);
}